// Round 7
// baseline (1678003.784 us; speedup 1.0000x reference)
//
#include <hip/hip_runtime.h>

// LSTM w/ hard-sigmoid gates. T=512, B=64, I=H=512.
// R7 = R4's proven step protocol (split-K waves, hbuf bf16 double-buffer,
// memset-zeroed monotonic flags, tid0 flag after full-WG barrier, single-load
// poll) + XCD-local cache scope, decided ONCE by an unbreakable vote:
//   every WG ORs (1<<XCC_ID) into xmask[rep] (ack-ordered), bumps a global
//   arrival counter; all spin to arr==NWG (arrival unconditional -> finite);
//   popcount(final mask)==1  => replica provably on ONE XCD -> flags+hbuf use
//   sc0 (per-XCD L2, ~5x lower RT); else sc0 sc1 (R4 semantics, 3x proven).
//   All WGs of a replica read the SAME final mask -> same mode (R5's fatal
//   mixed-mode race is structurally impossible).
// Geometry: 8 replicas x 8 batches x 16 WGs; rep = bid&7 so replica r's bids
// are {r, r+8, ...} -> one XCD under the measured bid%8 round-robin (m09).
// R6 lesson: LDS pad + per-wave flags were neutral/negative -> reverted to
// R4 flag scheme; pad kept (harmless).
//
// Workspace: [0,1024)    : xmask[8] @0, arr @64 (u32 idx)   -- memset 0
//            [1024,3072) : flags, 8 reps x 64 u32 (256B)    -- memset 0
//            [4096,+128K): h double buffer [2][64][512] bf16

#define T_LEN 512
#define BATCH 64
#define ISZ   512
#define HSZ   512

#define NREP 8
#define WPR  16
#define BR   8
#define JW   32
#define NWG  (NREP * WPR)
#define NTHR 512

typedef __bf16 bf16x8 __attribute__((ext_vector_type(8)));
typedef float  f32x4  __attribute__((ext_vector_type(4)));
typedef float  f32x8  __attribute__((ext_vector_type(8)));
typedef int    i32x4  __attribute__((ext_vector_type(4)));

__device__ __forceinline__ bf16x8 cvt8(f32x4 a, f32x4 b) {
  f32x8 t;
  t[0]=a[0]; t[1]=a[1]; t[2]=a[2]; t[3]=a[3];
  t[4]=b[0]; t[5]=b[1]; t[6]=b[2]; t[7]=b[3];
  return __builtin_convertvector(t, bf16x8);
}

__device__ __forceinline__ float fast_tanh(float v) {
  float e = __expf(2.0f * v);
  return 1.0f - 2.0f / (e + 1.0f);
}

__device__ __forceinline__ float hsig(float v) {
  return fminf(fmaxf(0.2f * v + 0.5f, 0.0f), 1.0f);
}

__device__ __forceinline__ unsigned pack_bf16(float a, float b) {
  union { __bf16 h[2]; unsigned u; } p;
  p.h[0] = (__bf16)a; p.h[1] = (__bf16)b;
  return p.u;
}

// mode-scoped ops. L: sc0 (per-XCD L2). G: sc0 sc1 (device-coherent point).
template<bool L>
__device__ __forceinline__ void st_u32(unsigned* p, unsigned v) {
  if constexpr (L) asm volatile("global_store_dword %0, %1, off sc0"     :: "v"(p), "v"(v) : "memory");
  else             asm volatile("global_store_dword %0, %1, off sc0 sc1" :: "v"(p), "v"(v) : "memory");
}
template<bool L>
__device__ __forceinline__ unsigned ld_u32(const unsigned* p) {
  unsigned v;
  if constexpr (L) asm volatile("global_load_dword %0, %1, off sc0\ns_waitcnt vmcnt(0)"     : "=v"(v) : "v"(p) : "memory");
  else             asm volatile("global_load_dword %0, %1, off sc0 sc1\ns_waitcnt vmcnt(0)" : "=v"(v) : "v"(p) : "memory");
  return v;
}
#define HL_L(i, o) asm volatile("global_load_dwordx4 %0, %1, off offset:" #o " sc0"     : "=v"(hfrag[i]) : "v"(hr));
#define HL_G(i, o) asm volatile("global_load_dwordx4 %0, %1, off offset:" #o " sc0 sc1" : "=v"(hfrag[i]) : "v"(hr));
#define XLOAD(i, o) asm volatile("global_load_dwordx4 %0, %1, off offset:" #o           : "=v"(xpre[i]) : "v"(xr));

template<bool L>
__device__ __forceinline__ void run_loop(
    const float* __restrict__ x, const float* __restrict__ h0,
    float* __restrict__ out, unsigned* __restrict__ myf,
    __bf16* __restrict__ hbuf, const bf16x8* wfrag, f32x4 bias4, float cst,
    f32x4* lds_p, int B0, int J0, int wgi, int tid, int lane, int wv,
    int l15, int hi, int lk, bool xw, int K0, int act, size_t urow) {
  unsigned* hbuf32 = (unsigned*)hbuf;

  // x[0] register prefetch (x-waves); overlaps h0 publish + flag RT
  f32x4 xpre[8];
  if (xw) {
    const float* xr = x + (size_t)(B0 + (l15 & 7)) * ISZ + K0 + lk;
    XLOAD(0, 0)   XLOAD(1, 16)  XLOAD(2, 128) XLOAD(3, 144)
    XLOAD(4, 256) XLOAD(5, 272) XLOAD(6, 384) XLOAD(7, 400)
  }

  // h0 publish (act threads), full-WG drain, tid0 flag = 1
  if (act) {
    float hv0 = h0[urow];
    float hp  = __shfl_xor(hv0, 1);
    if (!(tid & 1))
      st_u32<L>(&hbuf32[urow >> 1], pack_bf16(hv0, hp));
  }
  __syncthreads();                   // per-wave vmcnt(0) drain before barrier
  if (tid == 0) st_u32<L>(myf + wgi, 1u);

  for (int t = 0; t < T_LEN; ++t) {
    f32x4 acc[8];
#pragma unroll
    for (int i = 0; i < 8; ++i) acc[i] = (f32x4)(0.0f);

    if (xw) {
      asm volatile("s_waitcnt vmcnt(0)" ::: "memory");   // x[t] arrived
      __builtin_amdgcn_sched_barrier(0);                 // rule #18
      bf16x8 bx[4];
#pragma unroll
      for (int ks = 0; ks < 4; ++ks) bx[ks] = cvt8(xpre[2 * ks], xpre[2 * ks + 1]);
#pragma unroll
      for (int tile = 0; tile < 8; ++tile)
#pragma unroll
        for (int ks = 0; ks < 4; ++ks)
          acc[tile] = __builtin_amdgcn_mfma_f32_16x16x32_bf16(
              wfrag[tile * 4 + ks], bx[ks], acc[tile], 0, 0, 0);
    } else {
      // wait until all 16 WGs of this replica published h_t
      const unsigned tgt = (unsigned)(t + 1);
      long g = 0;
      for (;;) {
        unsigned v = ld_u32<L>(myf + l15);
        if (__all((int)(v >= tgt))) break;
        __builtin_amdgcn_s_sleep(1);
        if (++g > (1L << 20)) break;   // safety: corrupt visibly, don't hang
      }
      __builtin_amdgcn_sched_barrier(0);

      const __bf16* hr = hbuf + (size_t)(t & 1) * BATCH * HSZ
                              + (size_t)(B0 + (l15 & 7)) * HSZ + K0 + lk;
      i32x4 hfrag[4];
      if constexpr (L) { HL_L(0, 0) HL_L(1, 64) HL_L(2, 128) HL_L(3, 192) }
      else             { HL_G(0, 0) HL_G(1, 64) HL_G(2, 128) HL_G(3, 192) }
      asm volatile("s_waitcnt vmcnt(0)" ::: "memory");
      __builtin_amdgcn_sched_barrier(0);                 // rule #18
#pragma unroll
      for (int tile = 0; tile < 8; ++tile)
#pragma unroll
        for (int ks = 0; ks < 4; ++ks)
          acc[tile] = __builtin_amdgcn_mfma_f32_16x16x32_bf16(
              wfrag[tile * 4 + ks], __builtin_bit_cast(bf16x8, hfrag[ks]),
              acc[tile], 0, 0, 0);
    }

#pragma unroll
    for (int tile = 0; tile < 8; ++tile)
      lds_p[(wv * 8 + tile) * 65 + l15 * 4 + hi] = acc[tile];

    __syncthreads();                  // #1: partials visible

    float hv = 0.0f;
    if (act) {
      f32x4 gsum = bias4;
#pragma unroll
      for (int w = 0; w < 8; ++w)
        gsum += lds_p[(w * 8 + ((tid & 31) >> 2)) * 65 + (tid >> 5) * 4 + (tid & 3)];

      float iv = hsig(gsum[0]), fv = hsig(gsum[1]), ov = hsig(gsum[3]);
      float gv = fast_tanh(gsum[2]);
      cst = fv * cst + iv * gv;
      hv = ov * fast_tanh(cst);

      float hp = __shfl_xor(hv, 1);
      if (!(tid & 1))
        st_u32<L>(&hbuf32[((size_t)((t + 1) & 1) * BATCH * HSZ + urow) >> 1],
                  pack_bf16(hv, hp));
    }

    __syncthreads();                  // #2: drains publishes (vmcnt per wave)
    if (tid == 0) st_u32<L>(myf + wgi, (unsigned)(t + 2));

    // off-critical-path: out/hn/cn stores (plain cached)
    if (act) {
      out[(size_t)t * BATCH * HSZ + urow] = hv;
      if (t == T_LEN - 1) {
        out[(size_t)T_LEN * BATCH * HSZ + urow] = hv;                        // hn
        out[(size_t)T_LEN * BATCH * HSZ + (size_t)BATCH * HSZ + urow] = cst; // cn
      }
    }

    // x[t+1] register prefetch -- a full step of latency cover
    if (xw && (t + 1) < T_LEN) {
      const float* xr = x + ((size_t)(t + 1) * BATCH + B0 + (l15 & 7)) * ISZ + K0 + lk;
      XLOAD(0, 0)   XLOAD(1, 16)  XLOAD(2, 128) XLOAD(3, 144)
      XLOAD(4, 256) XLOAD(5, 272) XLOAD(6, 384) XLOAD(7, 400)
    }
  }
}

__global__ __launch_bounds__(NTHR, 2) void lstm_kernel(
    const float* __restrict__ x, const float* __restrict__ h0,
    const float* __restrict__ c0, const float* __restrict__ w_ih,
    const float* __restrict__ w_hh, const float* __restrict__ b_ih,
    const float* __restrict__ b_hh, float* __restrict__ out,
    unsigned* __restrict__ ws_u32, __bf16* __restrict__ hbuf) {
  const int bid = blockIdx.x;
  const int rep = bid & 7;            // = XCD id if bid%8 round-robin holds
  const int wgi = bid >> 3;           // 0..15
  const int B0  = rep * BR;
  const int J0  = wgi * JW;

  const int tid  = threadIdx.x;
  const int lane = tid & 63;
  const int wv   = tid >> 6;
  const int l15  = lane & 15;
  const int hi   = lane >> 4;
  const int lk   = hi << 3;
  const bool xw  = (wv < 4);
  const int  K0  = (wv & 3) * 128;

  unsigned* xmask = ws_u32;           // [8]
  unsigned* arr   = ws_u32 + 64;
  unsigned* myf   = ws_u32 + 256 + rep * 64;   // flags, 256B per replica

  // ---- weights -> registers (rows = 4*j_local + gate; K-slice per wave) ----
  bf16x8 wfrag[32];
  {
    const float* W = xw ? w_ih : w_hh;
#pragma unroll
    for (int tile = 0; tile < 8; ++tile) {
      const int r    = tile * 16 + l15;
      const int grow = (r & 3) * HSZ + J0 + (r >> 2);
      const float* wp = W + (size_t)grow * 512 + K0 + lk;
#pragma unroll
      for (int ks = 0; ks < 4; ++ks) {
        f32x4 a = *(const f32x4*)(wp + ks * 32);
        f32x4 b = *(const f32x4*)(wp + ks * 32 + 4);
        wfrag[tile * 4 + ks] = cvt8(a, b);
      }
    }
  }

  // ---- update-phase state ----
  const int act = (tid < 256);        // 8 batches x 32 cols
  const int ub  = tid >> 5;           // 0..7 when act
  const int uj  = tid & 31;
  const size_t urow = (size_t)(B0 + (ub & 7)) * HSZ + (size_t)(J0 + uj);

  f32x4 bias4;
#pragma unroll
  for (int q = 0; q < 4; ++q)
    bias4[q] = b_ih[q * HSZ + J0 + uj] + b_hh[q * HSZ + J0 + uj];
  float cst = act ? c0[urow] : 0.0f;

  // ==== unbreakable XCD vote ====
  unsigned xcc;
  asm volatile("s_getreg_b32 %0, hwreg(HW_REG_XCC_ID)" : "=s"(xcc));
  if (tid == 0) {
    unsigned old = __hip_atomic_fetch_or(&xmask[rep], 1u << (xcc & 31u),
                                         __ATOMIC_RELAXED, __HIP_MEMORY_SCOPE_AGENT);
    asm volatile("s_waitcnt vmcnt(0)" :: "v"(old) : "memory");  // OR acked first
    __hip_atomic_fetch_add(arr, 1u, __ATOMIC_RELAXED, __HIP_MEMORY_SCOPE_AGENT);
  }
  {
    long g = 0;   // arrival is unconditional -> terminates; guard astronomical
    while (__hip_atomic_load(arr, __ATOMIC_RELAXED, __HIP_MEMORY_SCOPE_AGENT) < (unsigned)NWG) {
      __builtin_amdgcn_s_sleep(8);
      if (++g > (1L << 26)) break;
    }
  }
  const unsigned msk = __hip_atomic_load(&xmask[rep], __ATOMIC_RELAXED,
                                         __HIP_MEMORY_SCOPE_AGENT);
  const bool mlocal = (__popc(msk) == 1);   // identical across the replica

  __shared__ __align__(16) f32x4 lds_p[8 * 8 * 65];

  if (mlocal)
    run_loop<true >(x, h0, out, myf, hbuf, wfrag, bias4, cst, lds_p,
                    B0, J0, wgi, tid, lane, wv, l15, hi, lk, xw, K0, act, urow);
  else
    run_loop<false>(x, h0, out, myf, hbuf, wfrag, bias4, cst, lds_p,
                    B0, J0, wgi, tid, lane, wv, l15, hi, lk, xw, K0, act, urow);
}

extern "C" void kernel_launch(void* const* d_in, const int* in_sizes, int n_in,
                              void* d_out, int out_size, void* d_ws, size_t ws_size,
                              hipStream_t stream) {
  const float* x    = (const float*)d_in[0];
  const float* h0   = (const float*)d_in[1];
  const float* c0   = (const float*)d_in[2];
  const float* w_ih = (const float*)d_in[3];
  const float* w_hh = (const float*)d_in[4];
  const float* b_ih = (const float*)d_in[5];
  const float* b_hh = (const float*)d_in[6];
  float* out = (float*)d_out;

  unsigned* ws_u32 = (unsigned*)d_ws;
  __bf16* hbuf     = (__bf16*)((char*)d_ws + 4096);
  // needs 4096 + 2*64*512*2 = ~132KB of workspace

  hipMemsetAsync(d_ws, 0, 4096, stream);  // zero vote words + flags each launch

  hipLaunchKernelGGL(lstm_kernel, dim3(NWG), dim3(NTHR), 0, stream,
                     x, h0, c0, w_ih, w_hh, b_ih, b_hh, out, ws_u32, hbuf);
}

// Round 8
// 1765.890 us; speedup vs baseline: 950.2310x; 950.2310x over previous
//
#include <hip/hip_runtime.h>

// LSTM w/ hard-sigmoid gates. T=512, B=64, I=H=512.
// R8 = R4's proven structure (split-K: 4 replicas x 16 batches x 16 WGs;
// x-waves 0-3 w_ih + register-prefetch x[t+1]; h-waves 4-7 w_hh; LDS partial
// reduce; lane-local cell update) with the flag protocol REPLACED by
// SELF-TAGGED h words:
//   h word u32 = (tag << 16) | bf16(h),  tag = step + 7  (unique in-launch;
//   0x0000/0xAAAA poison never matches). A 4B aligned store is atomic, so
//   data+version arrive together: no publish drain, no flag store, no separate
//   h load -- the consumer's tag-poll loop IS the h load (saves ~2 RTs/step).
// Slot-parity reuse is race-free: no WG can publish h_{t+2} before every WG
// of the replica finished reading h_t (publish <= update <= own poll done).
// hbuf is memset-zeroed in-graph each launch -> no cross-replay staleness.
// R7 lesson: grid-wide vote spin livelocked (writer starvation) -- abandoned.
//
// Workspace: [0, 256K): hbuf u32 [2][64][512] (memset 0 each launch)

#define T_LEN 512
#define BATCH 64
#define ISZ   512
#define HSZ   512

#define NREP 4
#define WPR  16
#define BR   16
#define JW   32
#define NWG  (NREP * WPR)
#define NTHR 512
#define TAG0 7u

typedef __bf16 bf16x8 __attribute__((ext_vector_type(8)));
typedef float  f32x4  __attribute__((ext_vector_type(4)));
typedef float  f32x8  __attribute__((ext_vector_type(8)));
typedef int    i32x4  __attribute__((ext_vector_type(4)));

__device__ __forceinline__ bf16x8 cvt8(f32x4 a, f32x4 b) {
  f32x8 t;
  t[0]=a[0]; t[1]=a[1]; t[2]=a[2]; t[3]=a[3];
  t[4]=b[0]; t[5]=b[1]; t[6]=b[2]; t[7]=b[3];
  return __builtin_convertvector(t, bf16x8);   // v_cvt_pk_bf16_f32 pairs
}

__device__ __forceinline__ float fast_tanh(float v) {
  float e = __expf(2.0f * v);
  return 1.0f - 2.0f / (e + 1.0f);   // exact limits at +-inf
}

__device__ __forceinline__ float hsig(float v) {
  return fminf(fmaxf(0.2f * v + 0.5f, 0.0f), 1.0f);
}

__device__ __forceinline__ unsigned tagword(float hv, unsigned tag) {
  union { __bf16 h[2]; unsigned u; } p;
  p.u = 0; p.h[0] = (__bf16)hv;                // RNE, same rounding as before
  return (tag << 16) | (p.u & 0xFFFFu);
}

// x prefetch: plain cached loads, asm-pinned so they issue at the step tail
#define XLOAD(i, o)                                                        \
  asm volatile("global_load_dwordx4 %0, %1, off offset:" #o                \
               : "=v"(xpre[i]) : "v"(xr));

__global__ __launch_bounds__(NTHR, 2) void lstm_kernel(
    const float* __restrict__ x,      // [T][B][I]
    const float* __restrict__ h0,     // [B][H]
    const float* __restrict__ c0,     // [B][H]
    const float* __restrict__ w_ih,   // [4H][I]
    const float* __restrict__ w_hh,   // [4H][H]
    const float* __restrict__ b_ih,   // [4H]
    const float* __restrict__ b_hh,   // [4H]
    float* __restrict__ out,          // [T][B][H] ++ hn[B][H] ++ cn[B][H]
    unsigned* __restrict__ hbuf32)    // [2][B][H] self-tagged h words
{
  const int bid = blockIdx.x;
  const int rep = bid >> 4;           // 0..3
  const int wgi = bid & 15;           // 0..15
  const int B0  = rep * BR;
  const int J0  = wgi * JW;

  const int tid  = threadIdx.x;
  const int lane = tid & 63;
  const int wv   = tid >> 6;          // 0..7
  const int l15  = lane & 15;
  const int hi   = lane >> 4;         // 0..3
  const int lk   = hi << 3;
  const bool xw  = (wv < 4);          // x-waves 0-3, h-waves 4-7
  const int  K0  = (wv & 3) * 128;    // this wave's K-slice base

  // ---- weights -> registers: 128 interleaved rows (row = 4*j_local + gate),
  //      K-slice [K0,K0+128) of w_ih (x-waves) or w_hh (h-waves) ----
  bf16x8 wfrag[32];                   // [tile 0..7][ks 0..3]
  {
    const float* W = xw ? w_ih : w_hh;
#pragma unroll
    for (int tile = 0; tile < 8; ++tile) {
      const int r    = tile * 16 + l15;              // WG-local row (A: row=l15)
      const int grow = (r & 3) * HSZ + J0 + (r >> 2);
      const float* wp = W + (size_t)grow * 512 + K0 + lk;
#pragma unroll
      for (int ks = 0; ks < 4; ++ks) {
        f32x4 a = *(const f32x4*)(wp + ks * 32);
        f32x4 b = *(const f32x4*)(wp + ks * 32 + 4);
        wfrag[tile * 4 + ks] = cvt8(a, b);
      }
    }
  }

  // ---- update-phase ids: thread owns (batch ub, column uj) ----
  const int ub     = tid >> 5;        // 0..15
  const int uj     = tid & 31;        // 0..31
  const int tile_u = uj >> 2;
  const int hi_u   = uj & 3;
  const size_t urow = (size_t)(B0 + ub) * HSZ + (size_t)(J0 + uj);

  f32x4 bias4;
#pragma unroll
  for (int q = 0; q < 4; ++q)
    bias4[q] = b_ih[q * HSZ + J0 + uj] + b_hh[q * HSZ + J0 + uj];

  float cst = c0[urow];

  // ---- x[0] register prefetch (x-waves) ----
  f32x4 xpre[8];
  if (xw) {
    const float* xr = x + (size_t)(B0 + l15) * ISZ + K0 + lk;
    XLOAD(0, 0)   XLOAD(1, 16)  XLOAD(2, 128) XLOAD(3, 144)
    XLOAD(4, 256) XLOAD(5, 272) XLOAD(6, 384) XLOAD(7, 400)
  }

  // ---- h0 publish: self-tagged words, tag TAG0, slot 0. No drain needed. ----
  __hip_atomic_store(&hbuf32[urow], tagword(h0[urow], TAG0),
                     __ATOMIC_RELAXED, __HIP_MEMORY_SCOPE_AGENT);

  // partials: [wave][tile] blocks of 65 f32x4 (64 data + 1 pad)
  __shared__ __align__(16) f32x4 lds_p[8 * 8 * 65];

  for (int t = 0; t < T_LEN; ++t) {
    f32x4 acc[8];
#pragma unroll
    for (int i = 0; i < 8; ++i) acc[i] = (f32x4)(0.0f);

    if (xw) {
      // x[t] prefetched last iteration; drain, keep MFMAs below (rule #18)
      asm volatile("s_waitcnt vmcnt(0)" ::: "memory");
      __builtin_amdgcn_sched_barrier(0);
      bf16x8 bx[4];
#pragma unroll
      for (int ks = 0; ks < 4; ++ks) bx[ks] = cvt8(xpre[2 * ks], xpre[2 * ks + 1]);
#pragma unroll
      for (int tile = 0; tile < 8; ++tile)
#pragma unroll
        for (int ks = 0; ks < 4; ++ks)
          acc[tile] = __builtin_amdgcn_mfma_f32_16x16x32_bf16(
              wfrag[tile * 4 + ks], bx[ks], acc[tile], 0, 0, 0);
    } else {
      // h-waves: poll-load self-tagged h_t (slot t&1, expect tag t+TAG0).
      // The poll IS the h load: retry all 8 dwordx4 until all 32 tags match.
      const unsigned* hp = hbuf32 + (size_t)(t & 1) * BATCH * HSZ
                                  + (size_t)(B0 + l15) * HSZ + K0 + lk;
      const unsigned exphi = (unsigned)(t + TAG0) << 16;
      i32x4 hw0, hw1, hw2, hw3, hw4, hw5, hw6, hw7;
      long g = 0;
      for (;;) {
        asm volatile(
            "global_load_dwordx4 %0, %8, off sc0 sc1\n\t"
            "global_load_dwordx4 %1, %8, off offset:16 sc0 sc1\n\t"
            "global_load_dwordx4 %2, %8, off offset:128 sc0 sc1\n\t"
            "global_load_dwordx4 %3, %8, off offset:144 sc0 sc1\n\t"
            "global_load_dwordx4 %4, %8, off offset:256 sc0 sc1\n\t"
            "global_load_dwordx4 %5, %8, off offset:272 sc0 sc1\n\t"
            "global_load_dwordx4 %6, %8, off offset:384 sc0 sc1\n\t"
            "global_load_dwordx4 %7, %8, off offset:400 sc0 sc1\n\t"
            "s_waitcnt vmcnt(0)"
            : "=&v"(hw0), "=&v"(hw1), "=&v"(hw2), "=&v"(hw3),
              "=&v"(hw4), "=&v"(hw5), "=&v"(hw6), "=&v"(hw7)
            : "v"(hp) : "memory");
        unsigned bad = 0;
#pragma unroll
        for (int e = 0; e < 4; ++e) {
          bad |= ((unsigned)hw0[e] ^ exphi) & 0xFFFF0000u;
          bad |= ((unsigned)hw1[e] ^ exphi) & 0xFFFF0000u;
          bad |= ((unsigned)hw2[e] ^ exphi) & 0xFFFF0000u;
          bad |= ((unsigned)hw3[e] ^ exphi) & 0xFFFF0000u;
          bad |= ((unsigned)hw4[e] ^ exphi) & 0xFFFF0000u;
          bad |= ((unsigned)hw5[e] ^ exphi) & 0xFFFF0000u;
          bad |= ((unsigned)hw6[e] ^ exphi) & 0xFFFF0000u;
          bad |= ((unsigned)hw7[e] ^ exphi) & 0xFFFF0000u;
        }
        if (__all((int)(bad == 0))) break;
        __builtin_amdgcn_s_sleep(1);
        if (++g > (1L << 20)) break;   // safety: corrupt visibly, don't hang
      }
      __builtin_amdgcn_sched_barrier(0);

      // repack low16 halves -> bf16x8 frags (v_perm pairs), then MFMA
      i32x4 hq[4];
#pragma unroll
      for (int ks = 0; ks < 4; ++ks) {
        const i32x4 wlo = (ks == 0) ? hw0 : (ks == 1) ? hw2 : (ks == 2) ? hw4 : hw6;
        const i32x4 whi = (ks == 0) ? hw1 : (ks == 1) ? hw3 : (ks == 2) ? hw5 : hw7;
        hq[ks][0] = (wlo[0] & 0xFFFF) | (wlo[1] << 16);
        hq[ks][1] = (wlo[2] & 0xFFFF) | (wlo[3] << 16);
        hq[ks][2] = (whi[0] & 0xFFFF) | (whi[1] << 16);
        hq[ks][3] = (whi[2] & 0xFFFF) | (whi[3] << 16);
      }
#pragma unroll
      for (int tile = 0; tile < 8; ++tile)
#pragma unroll
        for (int ks = 0; ks < 4; ++ks)
          acc[tile] = __builtin_amdgcn_mfma_f32_16x16x32_bf16(
              wfrag[tile * 4 + ks], __builtin_bit_cast(bf16x8, hq[ks]),
              acc[tile], 0, 0, 0);
    }

#pragma unroll
    for (int tile = 0; tile < 8; ++tile)
      lds_p[(wv * 8 + tile) * 65 + l15 * 4 + hi] = acc[tile];

    __syncthreads();                   // #1: all partials visible

    // reduce 8 K-slices + bias -> (i,f,g,o) of (ub, uj); lane-local update
    f32x4 gsum = bias4;
#pragma unroll
    for (int w = 0; w < 8; ++w)
      gsum += lds_p[(w * 8 + tile_u) * 65 + ub * 4 + hi_u];

    float iv = hsig(gsum[0]), fv = hsig(gsum[1]), ov = hsig(gsum[3]);
    float gv = fast_tanh(gsum[2]);
    cst = fv * cst + iv * gv;
    float hv = ov * fast_tanh(cst);

    // publish h_{t+1}: single self-tagged atomic dword, fire-and-forget
    __hip_atomic_store(
        &hbuf32[(size_t)((t + 1) & 1) * BATCH * HSZ + urow],
        tagword(hv, (unsigned)(t + 1 + TAG0)),
        __ATOMIC_RELAXED, __HIP_MEMORY_SCOPE_AGENT);

    // off-critical-path: out/hn/cn stores (plain cached)
    out[(size_t)t * BATCH * HSZ + urow] = hv;
    if (t == T_LEN - 1) {
      out[(size_t)T_LEN * BATCH * HSZ + urow] = hv;                        // hn
      out[(size_t)T_LEN * BATCH * HSZ + (size_t)BATCH * HSZ + urow] = cst; // cn
    }

    __syncthreads();                   // #2: protect lds_p reuse next iter

    // x[t+1] register prefetch -- a full step of latency cover
    if (xw && (t + 1) < T_LEN) {
      const float* xr = x + ((size_t)(t + 1) * BATCH + B0 + l15) * ISZ + K0 + lk;
      XLOAD(0, 0)   XLOAD(1, 16)  XLOAD(2, 128) XLOAD(3, 144)
      XLOAD(4, 256) XLOAD(5, 272) XLOAD(6, 384) XLOAD(7, 400)
    }
  }
}

extern "C" void kernel_launch(void* const* d_in, const int* in_sizes, int n_in,
                              void* d_out, int out_size, void* d_ws, size_t ws_size,
                              hipStream_t stream) {
  const float* x    = (const float*)d_in[0];
  const float* h0   = (const float*)d_in[1];
  const float* c0   = (const float*)d_in[2];
  const float* w_ih = (const float*)d_in[3];
  const float* w_hh = (const float*)d_in[4];
  const float* b_ih = (const float*)d_in[5];
  const float* b_hh = (const float*)d_in[6];
  float* out = (float*)d_out;

  unsigned* hbuf32 = (unsigned*)d_ws;
  // needs 2*64*512*4 = 256KB of workspace

  // zero all tags each launch: poison/stale never matches tag range [7,519]
  hipMemsetAsync(d_ws, 0, 2 * BATCH * HSZ * 4, stream);

  hipLaunchKernelGGL(lstm_kernel, dim3(NWG), dim3(NTHR), 0, stream,
                     x, h0, c0, w_ih, w_hh, b_ih, b_hh, out, hbuf32);
}

// Round 10
// 1490.837 us; speedup vs baseline: 1125.5450x; 1.1845x over previous
//
#include <hip/hip_runtime.h>

// LSTM w/ hard-sigmoid gates. T=512, B=64, I=H=512.
// R10 = R9 with the intra-WG xflag handshake ordering FIXED (R9's failure,
// absmax 2.7e-2, matched the stale-partial signature: relaxed LDS atomics let
// the compiler hoist wave 0's lds_p partial reads above the spin loop --
// rule #18's pattern). Fix: RELEASE store (+ explicit lgkm drain) on the
// producer, ACQUIRE load on the poll, sched_barrier(0)+memory clobber after.
// Structure (unchanged from R9):
//  - 8 replicas x 8 batches x 16 WGs (128 WGs): halved partial volume
//    (B-frag lanes 8-15 duplicate 0-7; LDS writes masked l15<8).
//  - x-partials pre-reduced OFF-CHAIN during the h-poll window (x-waves 1-3
//    write partials + flag; x-wave 0 sums into xsum). On-chain reduce =
//    xsum + 4 h-partials (was 8 reads).
//  - Cross-WG: byte-level R4 protocol (memset-zeroed monotonic flags, tid0
//    flag after barrier #2, single-load poll, bf16 hbuf dbuf, sc0sc1).
//
// Workspace: [0,4096)    : flags, 8 reps x 64 u32 (256B apart) -- memset 0
//            [4096,+128K): h double buffer [2][64][512] bf16

#define T_LEN 512
#define BATCH 64
#define ISZ   512
#define HSZ   512

#define NREP 8
#define WPR  16
#define BR   8
#define JW   32
#define NWG  (NREP * WPR)
#define NTHR 512

// LDS f32x4 slot indices (stride 33 per 32-slot tile block)
#define HP(w2, tile) (((w2) * 8 + (tile)) * 33)            // 4 blocks: h partials
#define XP(w2, tile) (1056 + ((w2) * 8 + (tile)) * 33)     // 3 blocks: x partials
#define XS(tile)     (1848 + (tile) * 33)                  // 1 block : x sum
#define LDS_SLOTS    2112

typedef __bf16 bf16x8 __attribute__((ext_vector_type(8)));
typedef float  f32x4  __attribute__((ext_vector_type(4)));
typedef float  f32x8  __attribute__((ext_vector_type(8)));
typedef int    i32x4  __attribute__((ext_vector_type(4)));

__device__ __forceinline__ bf16x8 cvt8(f32x4 a, f32x4 b) {
  f32x8 t;
  t[0]=a[0]; t[1]=a[1]; t[2]=a[2]; t[3]=a[3];
  t[4]=b[0]; t[5]=b[1]; t[6]=b[2]; t[7]=b[3];
  return __builtin_convertvector(t, bf16x8);   // v_cvt_pk_bf16_f32 pairs
}

__device__ __forceinline__ float fast_tanh(float v) {
  float e = __expf(2.0f * v);
  return 1.0f - 2.0f / (e + 1.0f);   // exact limits at +-inf
}

__device__ __forceinline__ float hsig(float v) {
  return fminf(fmaxf(0.2f * v + 0.5f, 0.0f), 1.0f);
}

__device__ __forceinline__ unsigned pack_bf16(float a, float b) {
  union { __bf16 h[2]; unsigned u; } p;
  p.h[0] = (__bf16)a; p.h[1] = (__bf16)b;
  return p.u;
}

// h loads: sc0 sc1 = bypass L1/L2, served at the device-coherent point
#define HLOAD(i, o)                                                        \
  asm volatile("global_load_dwordx4 %0, %1, off offset:" #o " sc0 sc1"     \
               : "=v"(hfrag[i]) : "v"(hr));
// x prefetch: plain cached loads, asm-pinned so they issue at the step tail
#define XLOAD(i, o)                                                        \
  asm volatile("global_load_dwordx4 %0, %1, off offset:" #o                \
               : "=v"(xpre[i]) : "v"(xr));

__global__ __launch_bounds__(NTHR, 2) void lstm_kernel(
    const float* __restrict__ x,      // [T][B][I]
    const float* __restrict__ h0,     // [B][H]
    const float* __restrict__ c0,     // [B][H]
    const float* __restrict__ w_ih,   // [4H][I]
    const float* __restrict__ w_hh,   // [4H][H]
    const float* __restrict__ b_ih,   // [4H]
    const float* __restrict__ b_hh,   // [4H]
    float* __restrict__ out,          // [T][B][H] ++ hn[B][H] ++ cn[B][H]
    unsigned* __restrict__ flags,     // [NREP][16] monotonic words, 256B/rep
    __bf16* __restrict__ hbuf)        // [2][B][H]
{
  const int bid = blockIdx.x;
  const int rep = bid >> 4;           // 0..7
  const int wgi = bid & 15;           // 0..15
  const int B0  = rep * BR;
  const int J0  = wgi * JW;

  const int tid  = threadIdx.x;
  const int lane = tid & 63;
  const int wv   = tid >> 6;          // 0..7
  const int l15  = lane & 15;
  const int hi   = lane >> 4;         // 0..3
  const int lk   = hi << 3;
  const bool xw  = (wv < 4);          // x-waves 0-3, h-waves 4-7
  const int  K0  = (wv & 3) * 128;    // this wave's K-slice base
  const int  b8  = l15 & 7;           // batch row (lanes 8-15 duplicate 0-7)

  unsigned* myf    = flags + rep * 64;
  unsigned* hbuf32 = (unsigned*)hbuf;

  // ---- weights -> registers: 128 interleaved rows (row = 4*j_local + gate),
  //      K-slice [K0,K0+128) of w_ih (x-waves) or w_hh (h-waves) ----
  bf16x8 wfrag[32];                   // [tile 0..7][ks 0..3]
  {
    const float* W = xw ? w_ih : w_hh;
#pragma unroll
    for (int tile = 0; tile < 8; ++tile) {
      const int r    = tile * 16 + l15;              // WG-local row (A: row=l15)
      const int grow = (r & 3) * HSZ + J0 + (r >> 2);
      const float* wp = W + (size_t)grow * 512 + K0 + lk;
#pragma unroll
      for (int ks = 0; ks < 4; ++ks) {
        f32x4 a = *(const f32x4*)(wp + ks * 32);
        f32x4 b = *(const f32x4*)(wp + ks * 32 + 4);
        wfrag[tile * 4 + ks] = cvt8(a, b);
      }
    }
  }

  // ---- update-phase ids: 256 act threads own (batch ub, column uj) ----
  const int act = (tid < 256);
  const int ub     = tid >> 5;        // 0..7 when act
  const int uj     = tid & 31;        // 0..31
  const int tile_u = uj >> 2;
  const int hi_u   = uj & 3;
  const size_t urow = (size_t)(B0 + (ub & 7)) * HSZ + (size_t)(J0 + uj);

  f32x4 bias4;
#pragma unroll
  for (int q = 0; q < 4; ++q)
    bias4[q] = b_ih[q * HSZ + J0 + uj] + b_hh[q * HSZ + J0 + uj];

  float cst = act ? c0[urow] : 0.0f;

  // ---- x[0] register prefetch (x-waves) ----
  f32x4 xpre[8];
  if (xw) {
    const float* xr = x + (size_t)(B0 + b8) * ISZ + K0 + lk;
    XLOAD(0, 0)   XLOAD(1, 16)  XLOAD(2, 128) XLOAD(3, 144)
    XLOAD(4, 256) XLOAD(5, 272) XLOAD(6, 384) XLOAD(7, 400)
  }

  __shared__ __align__(16) f32x4 lds_p[LDS_SLOTS];
  __shared__ unsigned xflag[3];       // x-waves 1-3 -> wave 0, monotonic t+1
  if (tid < 3)
    __hip_atomic_store(&xflag[tid], 0u, __ATOMIC_RELAXED,
                       __HIP_MEMORY_SCOPE_WORKGROUP);

  // ---- h0 publish (act, packed pairs), full-WG drain, tid0 flag = 1 ----
  if (act) {
    float hv0 = h0[urow];
    float hp  = __shfl_xor(hv0, 1);
    if (!(tid & 1))
      __hip_atomic_store(&hbuf32[urow >> 1], pack_bf16(hv0, hp),
                         __ATOMIC_RELAXED, __HIP_MEMORY_SCOPE_AGENT);
  }
  __syncthreads();                    // drains publishes + xflag init
  if (tid == 0)
    __hip_atomic_store(&myf[wgi], 1u, __ATOMIC_RELAXED, __HIP_MEMORY_SCOPE_AGENT);

  for (int t = 0; t < T_LEN; ++t) {
    f32x4 acc[8];
#pragma unroll
    for (int i = 0; i < 8; ++i) acc[i] = (f32x4)(0.0f);

    if (xw) {
      // x[t] prefetched last iteration; drain, keep MFMAs below (rule #18)
      asm volatile("s_waitcnt vmcnt(0)" ::: "memory");
      __builtin_amdgcn_sched_barrier(0);
      bf16x8 bx[4];
#pragma unroll
      for (int ks = 0; ks < 4; ++ks) bx[ks] = cvt8(xpre[2 * ks], xpre[2 * ks + 1]);
#pragma unroll
      for (int tile = 0; tile < 8; ++tile)
#pragma unroll
        for (int ks = 0; ks < 4; ++ks)
          acc[tile] = __builtin_amdgcn_mfma_f32_16x16x32_bf16(
              wfrag[tile * 4 + ks], bx[ks], acc[tile], 0, 0, 0);

      if (wv != 0) {
        // waves 1-3: partial -> LDS (masked), lgkm drain, RELEASE flag
#pragma unroll
        for (int tile = 0; tile < 8; ++tile)
          if (l15 < 8) lds_p[XP(wv - 1, tile) + b8 * 4 + hi] = acc[tile];
        asm volatile("s_waitcnt lgkmcnt(0)" ::: "memory");
        if (lane == 0)
          __hip_atomic_store(&xflag[wv - 1], (unsigned)(t + 1),
                             __ATOMIC_RELEASE, __HIP_MEMORY_SCOPE_WORKGROUP);
      } else {
        // wave 0: ACQUIRE-poll siblings, then sum 3 partials + own -> xsum.
        // Acquire forbids hoisting the lds_p reads above the spin (R9 bug).
        const unsigned tgt = (unsigned)(t + 1);
        long g = 0;
        for (;;) {
          unsigned f0 = __hip_atomic_load(&xflag[0], __ATOMIC_ACQUIRE, __HIP_MEMORY_SCOPE_WORKGROUP);
          unsigned f1 = __hip_atomic_load(&xflag[1], __ATOMIC_ACQUIRE, __HIP_MEMORY_SCOPE_WORKGROUP);
          unsigned f2 = __hip_atomic_load(&xflag[2], __ATOMIC_ACQUIRE, __HIP_MEMORY_SCOPE_WORKGROUP);
          if (f0 >= tgt && f1 >= tgt && f2 >= tgt) break;
          if (++g > (1L << 22)) break;   // safety: corrupt visibly, don't hang
        }
        asm volatile("" ::: "memory");       // compiler fence (insurance)
        __builtin_amdgcn_sched_barrier(0);   // machine-sched fence (rule #18)
#pragma unroll
        for (int tile = 0; tile < 8; ++tile) {
#pragma unroll
          for (int w2 = 0; w2 < 3; ++w2)
            acc[tile] += lds_p[XP(w2, tile) + b8 * 4 + hi];
          if (l15 < 8) lds_p[XS(tile) + b8 * 4 + hi] = acc[tile];
        }
      }
    } else {
      // h-waves: wait until all 16 WGs of this replica published h_t
      const unsigned tgt = (unsigned)(t + 1);
      long g = 0;
      for (;;) {
        unsigned v = __hip_atomic_load(&myf[l15], __ATOMIC_RELAXED,
                                       __HIP_MEMORY_SCOPE_AGENT);
        if (__all((int)(v >= tgt))) break;
        __builtin_amdgcn_s_sleep(1);
        if (++g > (1L << 20)) break;   // safety: corrupt visibly, don't hang
      }
      __builtin_amdgcn_sched_barrier(0);

      const __bf16* hr = hbuf + (size_t)(t & 1) * BATCH * HSZ
                              + (size_t)(B0 + b8) * HSZ + K0 + lk;
      i32x4 hfrag[4];
      HLOAD(0, 0) HLOAD(1, 64) HLOAD(2, 128) HLOAD(3, 192)
      asm volatile("s_waitcnt vmcnt(0)" ::: "memory");
      __builtin_amdgcn_sched_barrier(0);   // rule #18: MFMAs stay below wait
#pragma unroll
      for (int tile = 0; tile < 8; ++tile)
#pragma unroll
        for (int ks = 0; ks < 4; ++ks)
          acc[tile] = __builtin_amdgcn_mfma_f32_16x16x32_bf16(
              wfrag[tile * 4 + ks], __builtin_bit_cast(bf16x8, hfrag[ks]),
              acc[tile], 0, 0, 0);

      // h partial -> LDS (masked to real batches); barrier #1 orders it
#pragma unroll
      for (int tile = 0; tile < 8; ++tile)
        if (l15 < 8) lds_p[HP(wv - 4, tile) + b8 * 4 + hi] = acc[tile];
    }

    __syncthreads();                   // #1: xsum + h partials visible

    float hv = 0.0f;
    if (act) {
      // reduce: xsum + 4 h-partials + bias -> (i,f,g,o) of (ub, uj)
      f32x4 gsum = bias4 + lds_p[XS(tile_u) + ub * 4 + hi_u];
#pragma unroll
      for (int w2 = 0; w2 < 4; ++w2)
        gsum += lds_p[HP(w2, tile_u) + ub * 4 + hi_u];

      float iv = hsig(gsum[0]), fv = hsig(gsum[1]), ov = hsig(gsum[3]);
      float gv = fast_tanh(gsum[2]);
      cst = fv * cst + iv * gv;
      hv = ov * fast_tanh(cst);

      // publish h_{t+1} (packed u32 pairs)
      float hp = __shfl_xor(hv, 1);
      if (!(tid & 1))
        __hip_atomic_store(
            &hbuf32[((size_t)((t + 1) & 1) * BATCH * HSZ + urow) >> 1],
            pack_bf16(hv, hp), __ATOMIC_RELAXED, __HIP_MEMORY_SCOPE_AGENT);
    }

    __syncthreads();                   // #2: drains publishes (vmcnt per wave)
    if (tid == 0)
      __hip_atomic_store(&myf[wgi], (unsigned)(t + 2), __ATOMIC_RELAXED,
                         __HIP_MEMORY_SCOPE_AGENT);

    // off-critical-path: out/hn/cn stores (plain cached)
    if (act) {
      out[(size_t)t * BATCH * HSZ + urow] = hv;
      if (t == T_LEN - 1) {
        out[(size_t)T_LEN * BATCH * HSZ + urow] = hv;                        // hn
        out[(size_t)T_LEN * BATCH * HSZ + (size_t)BATCH * HSZ + urow] = cst; // cn
      }
    }

    // x[t+1] register prefetch -- a full step of latency cover
    if (xw && (t + 1) < T_LEN) {
      const float* xr = x + ((size_t)(t + 1) * BATCH + B0 + b8) * ISZ + K0 + lk;
      XLOAD(0, 0)   XLOAD(1, 16)  XLOAD(2, 128) XLOAD(3, 144)
      XLOAD(4, 256) XLOAD(5, 272) XLOAD(6, 384) XLOAD(7, 400)
    }
  }
}

extern "C" void kernel_launch(void* const* d_in, const int* in_sizes, int n_in,
                              void* d_out, int out_size, void* d_ws, size_t ws_size,
                              hipStream_t stream) {
  const float* x    = (const float*)d_in[0];
  const float* h0   = (const float*)d_in[1];
  const float* c0   = (const float*)d_in[2];
  const float* w_ih = (const float*)d_in[3];
  const float* w_hh = (const float*)d_in[4];
  const float* b_ih = (const float*)d_in[5];
  const float* b_hh = (const float*)d_in[6];
  float* out = (float*)d_out;

  unsigned* flags = (unsigned*)d_ws;
  __bf16* hbuf    = (__bf16*)((char*)d_ws + 4096);
  // needs 4096 + 2*64*512*2 = ~132KB of workspace

  hipMemsetAsync(d_ws, 0, 4096, stream);  // zero flag words (ws is poisoned)

  hipLaunchKernelGGL(lstm_kernel, dim3(NWG), dim3(NTHR), 0, stream,
                     x, h0, c0, w_ih, w_hh, b_ih, b_hh, out, flags, hbuf);
}